// Round 1
// 655.140 us; speedup vs baseline: 1.1039x; 1.1039x over previous
//
#include <hip/hip_runtime.h>

// TripletInteraction fused implementation (MI355X / gfx950).
// Inputs/weights/output are float32 per the reference; GEMMs run on
// v_mfma_f32_16x16x32_bf16 (f32 accum), intermediates bf16 (2% threshold).
// Workspace layout:
//   k0: pack weights -> bf16, transposed, k-contiguous     [ws+0, 144 KB)
//   k1: t = silu((silu(m_st@W1)*(rbf@W2))@W3)              [ws+256KB, +32 MB)
//   k2: per 128 edges: x = sum_j t[b1]*(cbf@Wc)/sqrt8 (LDS),
//       y = silu(x@Wd) (LDS), out = silu(y@Ws) -> d_out,
//       and (fast path) z = silu(y@Wt) -> ws zbuf (f32)    [ws+~32.3MB, +128 MB)
//   k3 fast: out[e] = (out[e] + z[idx_swap[e]]) * 1/sqrt2  (pure BW pass)
//   k3 slow (fallback if ws too small): old recompute path.
// All global reads are in-bounds by construction (indices staged + clamped).

#define DEV __device__ __forceinline__

typedef __attribute__((ext_vector_type(8))) short bf16x8;
typedef __attribute__((ext_vector_type(4))) float f32x4;

constexpr int E = 250000;
constexpr float INV_SQRT_2  = 0.70710678118654752f;
constexpr float INV_SQRT_NB = 0.35355339059327373f;

// pack offsets in u16 elements
constexpr int PW1 = 0;        // W_m_rbf^T [128][128]
constexpr int PW2 = 16384;    // W_rbf^T   [128][32]  (k>=16 zero)
constexpr int PW3 = 20480;    // W_m_cbf^T [64][128]
constexpr int PWD = 28672;    // W_dir^T   [128][64]
constexpr int PWS = 36864;    // W_st^T    [128][128]
constexpr int PWT = 53248;    // W_ts^T    [128][128]
constexpr int PWC = 69632;    // W_cbf^T   [64][40]   (k>=16 zero, padded)
constexpr int PACK_TOTAL = 72192;

constexpr size_t OFF_T = 1u << 18;                       // t-table at ws+256KB, E*64 bf16 = 32 MB
constexpr size_t OFF_Z = OFF_T + (size_t)E * 64 * 2;     // 32,262,144 (16B aligned)
constexpr size_t WS_NEED_FAST = OFF_Z + (size_t)E * 128 * 4;  // ~160.3 MB

DEV unsigned short f2bf(float f) {
  unsigned u = __float_as_uint(f);
  return (unsigned short)((u + 0x7fffu + ((u >> 16) & 1u)) >> 16);
}
DEV float bf2f(unsigned short h) { return __uint_as_float((unsigned)h << 16); }
DEV float silu_f(float x) { return x / (1.f + __expf(-x)); }

// ---------------- K0: transpose+convert f32 weights into bf16 pack ----------------
__global__ __launch_bounds__(256) void k0_pack(
    const float* __restrict__ W1, const float* __restrict__ W2,
    const float* __restrict__ W3, const float* __restrict__ Wc,
    const float* __restrict__ Wd, const float* __restrict__ Ws,
    const float* __restrict__ Wt, unsigned short* __restrict__ pack) {
  int idx = blockIdx.x * 256 + threadIdx.x;
  if (idx >= PACK_TOTAL) return;
  float v = 0.f;
  if (idx < PW2)      { int i = idx;       int n = i >> 7, k = i & 127; v = W1[k * 128 + n]; }
  else if (idx < PW3) { int i = idx - PW2; int n = i >> 5, k = i & 31;  v = (k < 16) ? W2[k * 128 + n] : 0.f; }
  else if (idx < PWD) { int i = idx - PW3; int n = i >> 7, k = i & 127; v = W3[k * 64 + n]; }
  else if (idx < PWS) { int i = idx - PWD; int n = i >> 6, k = i & 63;  v = Wd[k * 128 + n]; }
  else if (idx < PWT) { int i = idx - PWS; int n = i >> 7, k = i & 127; v = Ws[k * 128 + n]; }
  else if (idx < PWC) { int i = idx - PWT; int n = i >> 7, k = i & 127; v = Wt[k * 128 + n]; }
  else                { int i = idx - PWC; int n = i / 40, k = i % 40;  v = (k < 16) ? Wc[k * 64 + n] : 0.f; }
  pack[idx] = f2bf(v);
}

// ---------------- K1: t = silu( (silu(m_st@W1) * (rbf@W2)) @ W3 ) ----------------
__global__ __launch_bounds__(512) void k1_mbranch(
    const float* __restrict__ m_st, const float* __restrict__ rbf,
    const unsigned short* __restrict__ pack, unsigned short* __restrict__ tT) {
  __shared__ __align__(16) unsigned short sA[128 * 136];
  __shared__ __align__(16) unsigned short sR[128 * 40];
  const int tid = threadIdx.x;
  const int e0 = blockIdx.x * 128;

  #pragma unroll
  for (int it = 0; it < 16; ++it) {
    int i = tid + it * 512;               // 8192 float2 chunks: 128 rows x 64
    int row = i >> 6, kh = i & 63;
    int er = min(e0 + row, E - 1);
    const float2 v = *(const float2*)(m_st + (size_t)er * 128 + kh * 2);
    unsigned pk = (unsigned)f2bf(v.x) | ((unsigned)f2bf(v.y) << 16);
    *(unsigned*)(sA + row * 136 + kh * 2) = pk;
  }
  #pragma unroll
  for (int it = 0; it < 4; ++it) {
    int i = tid + it * 512;               // 2048 chunks: 128 rows x 16
    int row = i >> 4, kh = i & 15;
    int er = min(e0 + row, E - 1);
    unsigned pk = 0;
    if (kh < 8) {
      const float2 v = *(const float2*)(rbf + (size_t)er * 16 + kh * 2);
      pk = (unsigned)f2bf(v.x) | ((unsigned)f2bf(v.y) << 16);
    }
    *(unsigned*)(sR + row * 40 + kh * 2) = pk;
  }
  __syncthreads();

  const int lane = tid & 63, wv = tid >> 6;
  const int m = lane & 15, q = lane >> 4;
  const int arow = wv * 16 + m;

  const f32x4 zero4 = {0.f, 0.f, 0.f, 0.f};
  f32x4 macc[8], racc[8];
  #pragma unroll
  for (int nt = 0; nt < 8; ++nt) { macc[nt] = zero4; racc[nt] = zero4; }

  { // rbf branch: K=32 (upper 16 zero-padded)
    bf16x8 a = *(const bf16x8*)(sR + arow * 40 + q * 8);
    #pragma unroll
    for (int nt = 0; nt < 8; ++nt) {
      bf16x8 b = *(const bf16x8*)(pack + PW2 + (nt * 16 + m) * 32 + q * 8);
      racc[nt] = __builtin_amdgcn_mfma_f32_16x16x32_bf16(a, b, racc[nt], 0, 0, 0);
    }
  }
  #pragma unroll
  for (int kk = 0; kk < 4; ++kk) { // m_st @ W_m_rbf
    bf16x8 a = *(const bf16x8*)(sA + arow * 136 + kk * 32 + q * 8);
    #pragma unroll
    for (int nt = 0; nt < 8; ++nt) {
      bf16x8 b = *(const bf16x8*)(pack + PW1 + (nt * 16 + m) * 128 + kk * 32 + q * 8);
      macc[nt] = __builtin_amdgcn_mfma_f32_16x16x32_bf16(a, b, macc[nt], 0, 0, 0);
    }
  }
  #pragma unroll
  for (int nt = 0; nt < 8; ++nt)
    #pragma unroll
    for (int r = 0; r < 4; ++r) {
      float v = silu_f(macc[nt][r]) * racc[nt][r];
      sA[(wv * 16 + q * 4 + r) * 136 + nt * 16 + m] = f2bf(v);
    }
  __syncthreads();

  f32x4 tacc[4];
  #pragma unroll
  for (int nt = 0; nt < 4; ++nt) tacc[nt] = zero4;
  #pragma unroll
  for (int kk = 0; kk < 4; ++kk) { // m @ W_m_cbf
    bf16x8 a = *(const bf16x8*)(sA + arow * 136 + kk * 32 + q * 8);
    #pragma unroll
    for (int nt = 0; nt < 4; ++nt) {
      bf16x8 b = *(const bf16x8*)(pack + PW3 + (nt * 16 + m) * 128 + kk * 32 + q * 8);
      tacc[nt] = __builtin_amdgcn_mfma_f32_16x16x32_bf16(a, b, tacc[nt], 0, 0, 0);
    }
  }
  #pragma unroll
  for (int r = 0; r < 4; ++r) {
    int erow = e0 + wv * 16 + q * 4 + r;
    if (erow < E) {
      ushort4 o;
      o.x = f2bf(silu_f(tacc[0][r]));
      o.y = f2bf(silu_f(tacc[1][r]));
      o.z = f2bf(silu_f(tacc[2][r]));
      o.w = f2bf(silu_f(tacc[3][r]));
      // permuted layout: t[row][m*4 + nt]  (col = nt*16 + m)
      *(ushort4*)(tT + (size_t)erow * 64 + m * 4) = o;
    }
  }
}

// Shared device helper: given staged basis indices sB[1024] (per local cbf2
// row) and per-lane cbf A-fragment, compute the x-tile for 16 local edges of
// wave wv and store into sX (stride 72). Rows a/b of each mt come from q0/q2.
DEV void xtile_gather_reduce(
    const float* __restrict__ cbf, const int* __restrict__ sB,
    const unsigned short* __restrict__ tT, const bf16x8* bw,
    unsigned short* __restrict__ sX,
    int wv, int m, int q, long long rowA, long long rowB, int mt) {
  bf16x8 af = {0, 0, 0, 0, 0, 0, 0, 0};
  if (q < 2) {
    long long row = (m < 8) ? rowA + m : rowB + (m - 8);
    const float4 c0 = *(const float4*)(cbf + row * 16 + q * 8);
    const float4 c1 = *(const float4*)(cbf + row * 16 + q * 8 + 4);
    af[0] = (short)f2bf(c0.x); af[1] = (short)f2bf(c0.y);
    af[2] = (short)f2bf(c0.z); af[3] = (short)f2bf(c0.w);
    af[4] = (short)f2bf(c1.x); af[5] = (short)f2bf(c1.y);
    af[6] = (short)f2bf(c1.z); af[7] = (short)f2bf(c1.w);
  }
  const f32x4 zero4 = {0.f, 0.f, 0.f, 0.f};
  f32x4 p0 = zero4, p1 = zero4, p2 = zero4, p3 = zero4;
  p0 = __builtin_amdgcn_mfma_f32_16x16x32_bf16(af, bw[0], p0, 0, 0, 0);
  p1 = __builtin_amdgcn_mfma_f32_16x16x32_bf16(af, bw[1], p1, 0, 0, 0);
  p2 = __builtin_amdgcn_mfma_f32_16x16x32_bf16(af, bw[2], p2, 0, 0, 0);
  p3 = __builtin_amdgcn_mfma_f32_16x16x32_bf16(af, bw[3], p3, 0, 0, 0);

  float s0 = 0.f, s1 = 0.f, s2 = 0.f, s3 = 0.f;
  const int lrb = wv * 128 + mt * 16;
  #pragma unroll
  for (int r = 0; r < 4; ++r) {
    int brow = sB[lrb + q * 4 + r];
    ushort4 tv = *(const ushort4*)(tT + (size_t)brow * 64 + m * 4);
    s0 += bf2f(tv.x) * p0[r];
    s1 += bf2f(tv.y) * p1[r];
    s2 += bf2f(tv.z) * p2[r];
    s3 += bf2f(tv.w) * p3[r];
  }
  s0 += __shfl_xor(s0, 16);
  s1 += __shfl_xor(s1, 16);
  s2 += __shfl_xor(s2, 16);
  s3 += __shfl_xor(s3, 16);

  int lrow = wv * 16 + mt * 2 + (q >> 1);   // q0 -> edge a, q2 -> edge b
  if (q == 0 || q == 2) {
    sX[lrow * 72 +  0 + m] = f2bf(s0 * INV_SQRT_NB);
    sX[lrow * 72 + 16 + m] = f2bf(s1 * INV_SQRT_NB);
    sX[lrow * 72 + 32 + m] = f2bf(s2 * INV_SQRT_NB);
    sX[lrow * 72 + 48 + m] = f2bf(s3 * INV_SQRT_NB);
  }
}

// y = silu(x @ Wd) from sX into sY (per-wave slab)
DEV void ytile(const unsigned short* __restrict__ pack,
               const unsigned short* __restrict__ sX,
               unsigned short* __restrict__ sY, int wv, int m, int q) {
  const int arow = wv * 16 + m;
  const f32x4 zero4 = {0.f, 0.f, 0.f, 0.f};
  f32x4 yacc[8];
  #pragma unroll
  for (int nt = 0; nt < 8; ++nt) yacc[nt] = zero4;
  #pragma unroll
  for (int kk = 0; kk < 2; ++kk) {
    bf16x8 a = *(const bf16x8*)(sX + arow * 72 + kk * 32 + q * 8);
    #pragma unroll
    for (int nt = 0; nt < 8; ++nt) {
      bf16x8 b = *(const bf16x8*)(pack + PWD + (nt * 16 + m) * 64 + kk * 32 + q * 8);
      yacc[nt] = __builtin_amdgcn_mfma_f32_16x16x32_bf16(a, b, yacc[nt], 0, 0, 0);
    }
  }
  #pragma unroll
  for (int nt = 0; nt < 8; ++nt)
    #pragma unroll
    for (int r = 0; r < 4; ++r)
      sY[(wv * 16 + q * 4 + r) * 136 + nt * 16 + m] = f2bf(silu_f(yacc[nt][r]));
}

// ---------------- K2: x (gather+reduce), y, out = silu(y@Ws), z = silu(y@Wt) ----------------
__global__ __launch_bounds__(512) void k2_fused(
    const float* __restrict__ cbf, const int* __restrict__ idx_s,
    const int* __restrict__ basis_idx1, const unsigned short* __restrict__ pack,
    const unsigned short* __restrict__ tT, float* __restrict__ out,
    float* __restrict__ zbuf) {
  __shared__ __align__(16) unsigned short sWc[64 * 40];
  __shared__ int sB1[1024];
  __shared__ __align__(16) unsigned short sX[128 * 72];
  __shared__ __align__(16) unsigned short sY[128 * 136];
  const int tid = threadIdx.x;
  const int e0 = blockIdx.x * 128;

  ((uint2*)sWc)[tid] = ((const uint2*)(pack + PWC))[tid];          // 512 chunks
  if (tid < 128) ((uint2*)sWc)[512 + tid] = ((const uint2*)(pack + PWC))[512 + tid];
  #pragma unroll
  for (int it = 0; it < 2; ++it) {
    int i = tid + it * 512;
    int e = min(e0 + (i >> 3), E - 1);
    int b = basis_idx1[idx_s[e] * 8 + (i & 7)];
    sB1[i] = min(max(b, 0), E - 1);
  }
  __syncthreads();

  const int lane = tid & 63, wv = tid >> 6;
  const int m = lane & 15, q = lane >> 4;

  bf16x8 bw[4];
  #pragma unroll
  for (int nt = 0; nt < 4; ++nt)
    bw[nt] = *(const bf16x8*)(sWc + (nt * 16 + m) * 40 + q * 8);

  for (int mt = 0; mt < 8; ++mt) {
    int ea = min(e0 + wv * 16 + mt * 2, E - 1);
    int eb = min(ea + 1, E - 1);
    xtile_gather_reduce(cbf, sB1, tT, bw, sX, wv, m, q,
                        (long long)ea * 8, (long long)eb * 8, mt);
  }
  __syncthreads();

  ytile(pack, sX, sY, wv, m, q);
  __syncthreads();

  const int arow = wv * 16 + m;
  const f32x4 zero4 = {0.f, 0.f, 0.f, 0.f};
  f32x4 acc[8];
  #pragma unroll
  for (int nt = 0; nt < 8; ++nt) acc[nt] = zero4;
  #pragma unroll
  for (int kk = 0; kk < 4; ++kk) {
    bf16x8 a = *(const bf16x8*)(sY + arow * 136 + kk * 32 + q * 8);
    #pragma unroll
    for (int nt = 0; nt < 8; ++nt) {
      bf16x8 b = *(const bf16x8*)(pack + PWS + (nt * 16 + m) * 128 + kk * 32 + q * 8);
      acc[nt] = __builtin_amdgcn_mfma_f32_16x16x32_bf16(a, b, acc[nt], 0, 0, 0);
    }
  }
  #pragma unroll
  for (int nt = 0; nt < 8; ++nt)
    #pragma unroll
    for (int r = 0; r < 4; ++r) {
      int erow = e0 + wv * 16 + q * 4 + r;
      if (erow < E) out[(size_t)erow * 128 + nt * 16 + m] = silu_f(acc[nt][r]);
    }

  if (zbuf) {  // fast path: also emit z = silu(y @ W_ts) for the swap-gather pass
    #pragma unroll
    for (int nt = 0; nt < 8; ++nt) acc[nt] = zero4;
    #pragma unroll
    for (int kk = 0; kk < 4; ++kk) {
      bf16x8 a = *(const bf16x8*)(sY + arow * 136 + kk * 32 + q * 8);
      #pragma unroll
      for (int nt = 0; nt < 8; ++nt) {
        bf16x8 b = *(const bf16x8*)(pack + PWT + (nt * 16 + m) * 128 + kk * 32 + q * 8);
        acc[nt] = __builtin_amdgcn_mfma_f32_16x16x32_bf16(a, b, acc[nt], 0, 0, 0);
      }
    }
    #pragma unroll
    for (int nt = 0; nt < 8; ++nt)
      #pragma unroll
      for (int r = 0; r < 4; ++r) {
        int erow = e0 + wv * 16 + q * 4 + r;
        if (erow < E) zbuf[(size_t)erow * 128 + nt * 16 + m] = silu_f(acc[nt][r]);
      }
  }
}

// ---------------- K3 fast: out[e] = (out[e] + z[idx_swap[e]]) / sqrt2 ----------------
// Pure bandwidth pass: 128 MB coalesced read + 128 MB row-gather (512 B
// contiguous per edge) + 128 MB write. One thread per float4 (E*32 total).
__global__ __launch_bounds__(256) void k3_combine(
    const int* __restrict__ idx_swap, const float* __restrict__ zbuf,
    float* __restrict__ out) {
  int t = blockIdx.x * 256 + threadIdx.x;
  int e = t >> 5, c = t & 31;
  if (e >= E) return;
  int f = idx_swap[e];
  f = min(max(f, 0), E - 1);
  float4 o = ((const float4*)out)[t];
  float4 z = ((const float4*)zbuf)[(size_t)f * 32 + c];
  o.x = (o.x + z.x) * INV_SQRT_2;
  o.y = (o.y + z.y) * INV_SQRT_2;
  o.z = (o.z + z.z) * INV_SQRT_2;
  o.w = (o.w + z.w) * INV_SQRT_2;
  ((float4*)out)[t] = o;
}

// ---------------- K3 slow (fallback): recompute z for f=idx_swap[e], RMW out ----------------
__global__ __launch_bounds__(512) void k3_swap(
    const float* __restrict__ cbf, const int* __restrict__ idx_s,
    const int* __restrict__ idx_swap, const int* __restrict__ basis_idx1,
    const unsigned short* __restrict__ pack, const unsigned short* __restrict__ tT,
    float* __restrict__ out) {
  __shared__ __align__(16) unsigned short sWc[64 * 40];
  __shared__ int sSE[128];
  __shared__ int sB3[1024];
  __shared__ __align__(16) unsigned short sX[128 * 72];
  __shared__ __align__(16) unsigned short sY[128 * 136];
  const int tid = threadIdx.x;
  const int e0 = blockIdx.x * 128;

  ((uint2*)sWc)[tid] = ((const uint2*)(pack + PWC))[tid];
  if (tid < 128) {
    ((uint2*)sWc)[512 + tid] = ((const uint2*)(pack + PWC))[512 + tid];
    int f = idx_swap[min(e0 + tid, E - 1)];
    sSE[tid] = min(max(f, 0), E - 1);
  }
  __syncthreads();
  #pragma unroll
  for (int it = 0; it < 2; ++it) {
    int i = tid + it * 512;
    int f = sSE[i >> 3];
    int b = basis_idx1[idx_s[f] * 8 + (i & 7)];
    sB3[i] = min(max(b, 0), E - 1);
  }
  __syncthreads();

  const int lane = tid & 63, wv = tid >> 6;
  const int m = lane & 15, q = lane >> 4;

  bf16x8 bw[4];
  #pragma unroll
  for (int nt = 0; nt < 4; ++nt)
    bw[nt] = *(const bf16x8*)(sWc + (nt * 16 + m) * 40 + q * 8);

  for (int mt = 0; mt < 8; ++mt) {
    int le = wv * 16 + mt * 2;
    long long fa = sSE[le], fb = sSE[le + 1];
    xtile_gather_reduce(cbf, sB3, tT, bw, sX, wv, m, q, fa * 8, fb * 8, mt);
  }
  __syncthreads();

  ytile(pack, sX, sY, wv, m, q);
  __syncthreads();

  const int arow = wv * 16 + m;
  const f32x4 zero4 = {0.f, 0.f, 0.f, 0.f};
  f32x4 acc[8];
  #pragma unroll
  for (int nt = 0; nt < 8; ++nt) acc[nt] = zero4;
  #pragma unroll
  for (int kk = 0; kk < 4; ++kk) {
    bf16x8 a = *(const bf16x8*)(sY + arow * 136 + kk * 32 + q * 8);
    #pragma unroll
    for (int nt = 0; nt < 8; ++nt) {
      bf16x8 b = *(const bf16x8*)(pack + PWT + (nt * 16 + m) * 128 + kk * 32 + q * 8);
      acc[nt] = __builtin_amdgcn_mfma_f32_16x16x32_bf16(a, b, acc[nt], 0, 0, 0);
    }
  }
  #pragma unroll
  for (int nt = 0; nt < 8; ++nt)
    #pragma unroll
    for (int r = 0; r < 4; ++r) {
      int erow = e0 + wv * 16 + q * 4 + r;
      if (erow < E) {
        size_t o = (size_t)erow * 128 + nt * 16 + m;
        out[o] = (out[o] + silu_f(acc[nt][r])) * INV_SQRT_2;
      }
    }
}

extern "C" void kernel_launch(void* const* d_in, const int* in_sizes, int n_in,
                              void* d_out, int out_size, void* d_ws, size_t ws_size,
                              hipStream_t stream) {
  const float* m_st = (const float*)d_in[0];
  const float* rbf  = (const float*)d_in[1];
  const float* cbf  = (const float*)d_in[2];
  const int* idx_s  = (const int*)d_in[3];
  const int* idx_sw = (const int*)d_in[4];
  const int* bidx   = (const int*)d_in[5];
  const float* W1 = (const float*)d_in[6];   // W_m_rbf 128x128
  const float* W2 = (const float*)d_in[7];   // W_rbf   16x128
  const float* W3 = (const float*)d_in[8];   // W_m_cbf 128x64
  const float* Wc = (const float*)d_in[9];   // W_cbf   16x64
  const float* Wd = (const float*)d_in[10];  // W_dir   64x128
  const float* Ws = (const float*)d_in[11];  // W_st    128x128
  const float* Wt = (const float*)d_in[12];  // W_ts    128x128

  unsigned short* pack = (unsigned short*)d_ws;
  unsigned short* tT   = (unsigned short*)((char*)d_ws + OFF_T);
  float* zbuf = (ws_size >= WS_NEED_FAST) ? (float*)((char*)d_ws + OFF_Z) : nullptr;
  float* out = (float*)d_out;

  const int nb = (E + 127) / 128;
  k0_pack<<<(PACK_TOTAL + 255) / 256, 256, 0, stream>>>(W1, W2, W3, Wc, Wd, Ws, Wt, pack);
  k1_mbranch<<<nb, 512, 0, stream>>>(m_st, rbf, pack, tT);
  k2_fused<<<nb, 512, 0, stream>>>(cbf, idx_s, bidx, pack, tT, out, zbuf);
  if (zbuf) {
    k3_combine<<<(E * 32 + 255) / 256, 256, 0, stream>>>(idx_sw, zbuf, out);
  } else {
    k3_swap<<<nb, 512, 0, stream>>>(cbf, idx_s, idx_sw, bidx, pack, tT, out);
  }
}

// Round 2
// 633.999 us; speedup vs baseline: 1.1407x; 1.0333x over previous
//
#include <hip/hip_runtime.h>

// TripletInteraction fused implementation (MI355X / gfx950).
// Inputs/weights/output are float32 per the reference; GEMMs run on
// v_mfma_f32_16x16x32_bf16 (f32 accum), intermediates bf16 (2% threshold).
// Workspace layout:
//   k0: pack weights -> bf16, transposed, k-contiguous     [ws+0, 144 KB)
//   k1: t = silu((silu(m_st@W1)*(rbf@W2))@W3)              [ws+256KB, +32 MB)
//   k2: per 128 edges: x = sum_j t[b1]*(cbf@Wc)/sqrt8 (LDS),
//       y = silu(x@Wd) (LDS), out = silu(y@Ws) -> d_out,
//       and (fast path) z = silu(y@Wt) -> ws zbuf (f32)    [ws+~32.3MB, +128 MB)
//       x-phase is software-pipelined (depth-2 prefetch of cbf + t-gathers)
//   k3 fast: out[e] = (out[e] + z[idx_swap[e]]) * 1/sqrt2  (pure BW pass)
//   k3 slow (fallback if ws too small): old recompute path.
// All global reads are in-bounds by construction (indices staged + clamped).

#define DEV __device__ __forceinline__

typedef __attribute__((ext_vector_type(8))) short bf16x8;
typedef __attribute__((ext_vector_type(4))) float f32x4;

constexpr int E = 250000;
constexpr float INV_SQRT_2  = 0.70710678118654752f;
constexpr float INV_SQRT_NB = 0.35355339059327373f;

// pack offsets in u16 elements
constexpr int PW1 = 0;        // W_m_rbf^T [128][128]
constexpr int PW2 = 16384;    // W_rbf^T   [128][32]  (k>=16 zero)
constexpr int PW3 = 20480;    // W_m_cbf^T [64][128]
constexpr int PWD = 28672;    // W_dir^T   [128][64]
constexpr int PWS = 36864;    // W_st^T    [128][128]
constexpr int PWT = 53248;    // W_ts^T    [128][128]
constexpr int PWC = 69632;    // W_cbf^T   [64][40]   (k>=16 zero, padded)
constexpr int PACK_TOTAL = 72192;

constexpr size_t OFF_T = 1u << 18;                       // t-table at ws+256KB, E*64 bf16 = 32 MB
constexpr size_t OFF_Z = OFF_T + (size_t)E * 64 * 2;     // 32,262,144 (16B aligned)
constexpr size_t WS_NEED_FAST = OFF_Z + (size_t)E * 128 * 4;  // ~160.3 MB

DEV unsigned short f2bf(float f) {
  unsigned u = __float_as_uint(f);
  return (unsigned short)((u + 0x7fffu + ((u >> 16) & 1u)) >> 16);
}
DEV float bf2f(unsigned short h) { return __uint_as_float((unsigned)h << 16); }
DEV float silu_f(float x) { return x / (1.f + __expf(-x)); }

// ---------------- K0: transpose+convert f32 weights into bf16 pack ----------------
__global__ __launch_bounds__(256) void k0_pack(
    const float* __restrict__ W1, const float* __restrict__ W2,
    const float* __restrict__ W3, const float* __restrict__ Wc,
    const float* __restrict__ Wd, const float* __restrict__ Ws,
    const float* __restrict__ Wt, unsigned short* __restrict__ pack) {
  int idx = blockIdx.x * 256 + threadIdx.x;
  if (idx >= PACK_TOTAL) return;
  float v = 0.f;
  if (idx < PW2)      { int i = idx;       int n = i >> 7, k = i & 127; v = W1[k * 128 + n]; }
  else if (idx < PW3) { int i = idx - PW2; int n = i >> 5, k = i & 31;  v = (k < 16) ? W2[k * 128 + n] : 0.f; }
  else if (idx < PWD) { int i = idx - PW3; int n = i >> 7, k = i & 127; v = W3[k * 64 + n]; }
  else if (idx < PWS) { int i = idx - PWD; int n = i >> 6, k = i & 63;  v = Wd[k * 128 + n]; }
  else if (idx < PWT) { int i = idx - PWS; int n = i >> 7, k = i & 127; v = Ws[k * 128 + n]; }
  else if (idx < PWC) { int i = idx - PWT; int n = i >> 7, k = i & 127; v = Wt[k * 128 + n]; }
  else                { int i = idx - PWC; int n = i / 40, k = i % 40;  v = (k < 16) ? Wc[k * 64 + n] : 0.f; }
  pack[idx] = f2bf(v);
}

// ---------------- K1: t = silu( (silu(m_st@W1) * (rbf@W2)) @ W3 ) ----------------
__global__ __launch_bounds__(512) void k1_mbranch(
    const float* __restrict__ m_st, const float* __restrict__ rbf,
    const unsigned short* __restrict__ pack, unsigned short* __restrict__ tT) {
  __shared__ __align__(16) unsigned short sA[128 * 136];
  __shared__ __align__(16) unsigned short sR[128 * 40];
  const int tid = threadIdx.x;
  const int e0 = blockIdx.x * 128;

  #pragma unroll
  for (int it = 0; it < 8; ++it) {
    int i = tid + it * 512;               // 4096 float4 chunks: 128 rows x 32
    int row = i >> 5, kh = i & 31;
    int er = min(e0 + row, E - 1);
    const float4 v = *(const float4*)(m_st + (size_t)er * 128 + kh * 4);
    ushort4 o;
    o.x = f2bf(v.x); o.y = f2bf(v.y); o.z = f2bf(v.z); o.w = f2bf(v.w);
    *(ushort4*)(sA + row * 136 + kh * 4) = o;
  }
  { // rbf: 128 rows x 4 float4 chunks = 512, one per thread
    int row = tid >> 2, kh = tid & 3;
    int er = min(e0 + row, E - 1);
    const float4 v = *(const float4*)(rbf + (size_t)er * 16 + kh * 4);
    ushort4 o;
    o.x = f2bf(v.x); o.y = f2bf(v.y); o.z = f2bf(v.z); o.w = f2bf(v.w);
    *(ushort4*)(sR + row * 40 + kh * 4) = o;
    // zero pad elements 16..31 (K=32 MFMA upper half)
    uint2 zz = {0u, 0u};
    *(uint2*)(sR + row * 40 + 16 + kh * 4) = zz;
  }
  __syncthreads();

  const int lane = tid & 63, wv = tid >> 6;
  const int m = lane & 15, q = lane >> 4;
  const int arow = wv * 16 + m;

  const f32x4 zero4 = {0.f, 0.f, 0.f, 0.f};
  f32x4 macc[8], racc[8];
  #pragma unroll
  for (int nt = 0; nt < 8; ++nt) { macc[nt] = zero4; racc[nt] = zero4; }

  { // rbf branch: K=32 (upper 16 zero-padded)
    bf16x8 a = *(const bf16x8*)(sR + arow * 40 + q * 8);
    #pragma unroll
    for (int nt = 0; nt < 8; ++nt) {
      bf16x8 b = *(const bf16x8*)(pack + PW2 + (nt * 16 + m) * 32 + q * 8);
      racc[nt] = __builtin_amdgcn_mfma_f32_16x16x32_bf16(a, b, racc[nt], 0, 0, 0);
    }
  }
  #pragma unroll
  for (int kk = 0; kk < 4; ++kk) { // m_st @ W_m_rbf
    bf16x8 a = *(const bf16x8*)(sA + arow * 136 + kk * 32 + q * 8);
    #pragma unroll
    for (int nt = 0; nt < 8; ++nt) {
      bf16x8 b = *(const bf16x8*)(pack + PW1 + (nt * 16 + m) * 128 + kk * 32 + q * 8);
      macc[nt] = __builtin_amdgcn_mfma_f32_16x16x32_bf16(a, b, macc[nt], 0, 0, 0);
    }
  }
  #pragma unroll
  for (int nt = 0; nt < 8; ++nt)
    #pragma unroll
    for (int r = 0; r < 4; ++r) {
      float v = silu_f(macc[nt][r]) * racc[nt][r];
      sA[(wv * 16 + q * 4 + r) * 136 + nt * 16 + m] = f2bf(v);
    }
  __syncthreads();

  f32x4 tacc[4];
  #pragma unroll
  for (int nt = 0; nt < 4; ++nt) tacc[nt] = zero4;
  #pragma unroll
  for (int kk = 0; kk < 4; ++kk) { // m @ W_m_cbf
    bf16x8 a = *(const bf16x8*)(sA + arow * 136 + kk * 32 + q * 8);
    #pragma unroll
    for (int nt = 0; nt < 4; ++nt) {
      bf16x8 b = *(const bf16x8*)(pack + PW3 + (nt * 16 + m) * 128 + kk * 32 + q * 8);
      tacc[nt] = __builtin_amdgcn_mfma_f32_16x16x32_bf16(a, b, tacc[nt], 0, 0, 0);
    }
  }
  #pragma unroll
  for (int r = 0; r < 4; ++r) {
    int erow = e0 + wv * 16 + q * 4 + r;
    if (erow < E) {
      ushort4 o;
      o.x = f2bf(silu_f(tacc[0][r]));
      o.y = f2bf(silu_f(tacc[1][r]));
      o.z = f2bf(silu_f(tacc[2][r]));
      o.w = f2bf(silu_f(tacc[3][r]));
      // permuted layout: t[row][m*4 + nt]  (col = nt*16 + m)
      *(ushort4*)(tT + (size_t)erow * 64 + m * 4) = o;
    }
  }
}

// ---- x-phase pipeline stages (used by k2 fast path) ----
// Issue stage: load cbf fragment (2x float4, lanes q<2) and 4 gathered t-rows.
DEV void x_issue(const float* __restrict__ cbf, const int* __restrict__ sB,
                 const unsigned short* __restrict__ tT,
                 int wv, int m, int q, int mt, long long rowA, long long rowB,
                 float4& c0, float4& c1, ushort4* tv) {
  if (q < 2) {
    long long row = (m < 8) ? rowA + m : rowB + (m - 8);
    c0 = *(const float4*)(cbf + row * 16 + q * 8);
    c1 = *(const float4*)(cbf + row * 16 + q * 8 + 4);
  }
  const int lrb = wv * 128 + mt * 16 + q * 4;
  #pragma unroll
  for (int r = 0; r < 4; ++r) {
    int brow = sB[lrb + r];
    tv[r] = *(const ushort4*)(tT + (size_t)brow * 64 + m * 4);
  }
}

// Compute stage: pack cbf -> bf16, 4 MFMA vs Wc, combine with t-rows, reduce,
// store x-tile row into sX (stride 72). Rows a/b of each mt come from q0/q2.
DEV void x_compute(const bf16x8* bw, unsigned short* __restrict__ sX,
                   int wv, int m, int q, int mt,
                   const float4& c0, const float4& c1,
                   const ushort4& tv0, const ushort4& tv1,
                   const ushort4& tv2, const ushort4& tv3) {
  bf16x8 af = {0, 0, 0, 0, 0, 0, 0, 0};
  if (q < 2) {
    af[0] = (short)f2bf(c0.x); af[1] = (short)f2bf(c0.y);
    af[2] = (short)f2bf(c0.z); af[3] = (short)f2bf(c0.w);
    af[4] = (short)f2bf(c1.x); af[5] = (short)f2bf(c1.y);
    af[6] = (short)f2bf(c1.z); af[7] = (short)f2bf(c1.w);
  }
  const f32x4 zero4 = {0.f, 0.f, 0.f, 0.f};
  f32x4 p0 = zero4, p1 = zero4, p2 = zero4, p3 = zero4;
  p0 = __builtin_amdgcn_mfma_f32_16x16x32_bf16(af, bw[0], p0, 0, 0, 0);
  p1 = __builtin_amdgcn_mfma_f32_16x16x32_bf16(af, bw[1], p1, 0, 0, 0);
  p2 = __builtin_amdgcn_mfma_f32_16x16x32_bf16(af, bw[2], p2, 0, 0, 0);
  p3 = __builtin_amdgcn_mfma_f32_16x16x32_bf16(af, bw[3], p3, 0, 0, 0);

  float s0 = bf2f(tv0.x) * p0[0] + bf2f(tv1.x) * p0[1] + bf2f(tv2.x) * p0[2] + bf2f(tv3.x) * p0[3];
  float s1 = bf2f(tv0.y) * p1[0] + bf2f(tv1.y) * p1[1] + bf2f(tv2.y) * p1[2] + bf2f(tv3.y) * p1[3];
  float s2 = bf2f(tv0.z) * p2[0] + bf2f(tv1.z) * p2[1] + bf2f(tv2.z) * p2[2] + bf2f(tv3.z) * p2[3];
  float s3 = bf2f(tv0.w) * p3[0] + bf2f(tv1.w) * p3[1] + bf2f(tv2.w) * p3[2] + bf2f(tv3.w) * p3[3];

  s0 += __shfl_xor(s0, 16);
  s1 += __shfl_xor(s1, 16);
  s2 += __shfl_xor(s2, 16);
  s3 += __shfl_xor(s3, 16);

  int lrow = wv * 16 + mt * 2 + (q >> 1);   // q0 -> edge a, q2 -> edge b
  if (q == 0 || q == 2) {
    sX[lrow * 72 +  0 + m] = f2bf(s0 * INV_SQRT_NB);
    sX[lrow * 72 + 16 + m] = f2bf(s1 * INV_SQRT_NB);
    sX[lrow * 72 + 32 + m] = f2bf(s2 * INV_SQRT_NB);
    sX[lrow * 72 + 48 + m] = f2bf(s3 * INV_SQRT_NB);
  }
}

// Legacy combined helper (used by fallback k3_swap only).
DEV void xtile_gather_reduce(
    const float* __restrict__ cbf, const int* __restrict__ sB,
    const unsigned short* __restrict__ tT, const bf16x8* bw,
    unsigned short* __restrict__ sX,
    int wv, int m, int q, long long rowA, long long rowB, int mt) {
  float4 c0, c1;
  ushort4 tv[4];
  x_issue(cbf, sB, tT, wv, m, q, mt, rowA, rowB, c0, c1, tv);
  x_compute(bw, sX, wv, m, q, mt, c0, c1, tv[0], tv[1], tv[2], tv[3]);
}

// y = silu(x @ Wd) from sX into sY (per-wave slab)
DEV void ytile(const unsigned short* __restrict__ pack,
               const unsigned short* __restrict__ sX,
               unsigned short* __restrict__ sY, int wv, int m, int q) {
  const int arow = wv * 16 + m;
  const f32x4 zero4 = {0.f, 0.f, 0.f, 0.f};
  f32x4 yacc[8];
  #pragma unroll
  for (int nt = 0; nt < 8; ++nt) yacc[nt] = zero4;
  #pragma unroll
  for (int kk = 0; kk < 2; ++kk) {
    bf16x8 a = *(const bf16x8*)(sX + arow * 72 + kk * 32 + q * 8);
    #pragma unroll
    for (int nt = 0; nt < 8; ++nt) {
      bf16x8 b = *(const bf16x8*)(pack + PWD + (nt * 16 + m) * 64 + kk * 32 + q * 8);
      yacc[nt] = __builtin_amdgcn_mfma_f32_16x16x32_bf16(a, b, yacc[nt], 0, 0, 0);
    }
  }
  #pragma unroll
  for (int nt = 0; nt < 8; ++nt)
    #pragma unroll
    for (int r = 0; r < 4; ++r)
      sY[(wv * 16 + q * 4 + r) * 136 + nt * 16 + m] = f2bf(silu_f(yacc[nt][r]));
}

// ---------------- K2: x (gather+reduce, pipelined), y, out = silu(y@Ws), z = silu(y@Wt) ----------------
__global__ __launch_bounds__(512, 4) void k2_fused(
    const float* __restrict__ cbf, const int* __restrict__ idx_s,
    const int* __restrict__ basis_idx1, const unsigned short* __restrict__ pack,
    const unsigned short* __restrict__ tT, float* __restrict__ out,
    float* __restrict__ zbuf) {
  __shared__ __align__(16) unsigned short sWc[64 * 40];
  __shared__ int sB1[1024];
  __shared__ __align__(16) unsigned short sX[128 * 72];
  __shared__ __align__(16) unsigned short sY[128 * 136];
  const int tid = threadIdx.x;
  const int e0 = blockIdx.x * 128;

  ((uint2*)sWc)[tid] = ((const uint2*)(pack + PWC))[tid];          // 512 chunks
  if (tid < 128) ((uint2*)sWc)[512 + tid] = ((const uint2*)(pack + PWC))[512 + tid];
  #pragma unroll
  for (int it = 0; it < 2; ++it) {
    int i = tid + it * 512;
    int e = min(e0 + (i >> 3), E - 1);
    int b = basis_idx1[idx_s[e] * 8 + (i & 7)];
    sB1[i] = min(max(b, 0), E - 1);
  }
  __syncthreads();

  const int lane = tid & 63, wv = tid >> 6;
  const int m = lane & 15, q = lane >> 4;

  bf16x8 bw[4];
  #pragma unroll
  for (int nt = 0; nt < 4; ++nt)
    bw[nt] = *(const bf16x8*)(sWc + (nt * 16 + m) * 40 + q * 8);

  // ---- software-pipelined x-phase (depth-2 prefetch) ----
  float4 pc0[2], pc1[2];
  ushort4 ptv[2][4];
  {
    int ea = min(e0 + wv * 16, E - 1), eb = min(ea + 1, E - 1);
    x_issue(cbf, sB1, tT, wv, m, q, 0, (long long)ea * 8, (long long)eb * 8,
            pc0[0], pc1[0], ptv[0]);
    ea = min(e0 + wv * 16 + 2, E - 1); eb = min(ea + 1, E - 1);
    x_issue(cbf, sB1, tT, wv, m, q, 1, (long long)ea * 8, (long long)eb * 8,
            pc0[1], pc1[1], ptv[1]);
  }
  #pragma unroll
  for (int mt = 0; mt < 8; ++mt) {
    const int s = mt & 1;   // compile-time after unroll
    float4 c0 = pc0[s], c1 = pc1[s];
    ushort4 tv0 = ptv[s][0], tv1 = ptv[s][1], tv2 = ptv[s][2], tv3 = ptv[s][3];
    if (mt + 2 < 8) {
      int ea = min(e0 + wv * 16 + (mt + 2) * 2, E - 1), eb = min(ea + 1, E - 1);
      x_issue(cbf, sB1, tT, wv, m, q, mt + 2, (long long)ea * 8, (long long)eb * 8,
              pc0[s], pc1[s], ptv[s]);
    }
    x_compute(bw, sX, wv, m, q, mt, c0, c1, tv0, tv1, tv2, tv3);
  }
  __syncthreads();

  ytile(pack, sX, sY, wv, m, q);
  __syncthreads();

  const int arow = wv * 16 + m;
  const f32x4 zero4 = {0.f, 0.f, 0.f, 0.f};
  f32x4 acc[8];
  #pragma unroll
  for (int nt = 0; nt < 8; ++nt) acc[nt] = zero4;
  #pragma unroll
  for (int kk = 0; kk < 4; ++kk) {
    bf16x8 a = *(const bf16x8*)(sY + arow * 136 + kk * 32 + q * 8);
    #pragma unroll
    for (int nt = 0; nt < 8; ++nt) {
      bf16x8 b = *(const bf16x8*)(pack + PWS + (nt * 16 + m) * 128 + kk * 32 + q * 8);
      acc[nt] = __builtin_amdgcn_mfma_f32_16x16x32_bf16(a, b, acc[nt], 0, 0, 0);
    }
  }
  #pragma unroll
  for (int nt = 0; nt < 8; ++nt)
    #pragma unroll
    for (int r = 0; r < 4; ++r) {
      int erow = e0 + wv * 16 + q * 4 + r;
      if (erow < E) out[(size_t)erow * 128 + nt * 16 + m] = silu_f(acc[nt][r]);
    }

  if (zbuf) {  // fast path: also emit z = silu(y @ W_ts) for the swap-gather pass
    #pragma unroll
    for (int nt = 0; nt < 8; ++nt) acc[nt] = zero4;
    #pragma unroll
    for (int kk = 0; kk < 4; ++kk) {
      bf16x8 a = *(const bf16x8*)(sY + arow * 136 + kk * 32 + q * 8);
      #pragma unroll
      for (int nt = 0; nt < 8; ++nt) {
        bf16x8 b = *(const bf16x8*)(pack + PWT + (nt * 16 + m) * 128 + kk * 32 + q * 8);
        acc[nt] = __builtin_amdgcn_mfma_f32_16x16x32_bf16(a, b, acc[nt], 0, 0, 0);
      }
    }
    #pragma unroll
    for (int nt = 0; nt < 8; ++nt)
      #pragma unroll
      for (int r = 0; r < 4; ++r) {
        int erow = e0 + wv * 16 + q * 4 + r;
        if (erow < E) zbuf[(size_t)erow * 128 + nt * 16 + m] = silu_f(acc[nt][r]);
      }
  }
}

// ---------------- K3 fast: out[e] = (out[e] + z[idx_swap[e]]) / sqrt2 ----------------
// Pure bandwidth pass: 128 MB coalesced read + 128 MB row-gather (512 B
// contiguous per edge) + 128 MB write. One thread per float4 (E*32 total).
__global__ __launch_bounds__(256) void k3_combine(
    const int* __restrict__ idx_swap, const float* __restrict__ zbuf,
    float* __restrict__ out) {
  int t = blockIdx.x * 256 + threadIdx.x;
  int e = t >> 5, c = t & 31;
  if (e >= E) return;
  int f = idx_swap[e];
  f = min(max(f, 0), E - 1);
  float4 o = ((const float4*)out)[t];
  float4 z = ((const float4*)zbuf)[(size_t)f * 32 + c];
  o.x = (o.x + z.x) * INV_SQRT_2;
  o.y = (o.y + z.y) * INV_SQRT_2;
  o.z = (o.z + z.z) * INV_SQRT_2;
  o.w = (o.w + z.w) * INV_SQRT_2;
  ((float4*)out)[t] = o;
}

// ---------------- K3 slow (fallback): recompute z for f=idx_swap[e], RMW out ----------------
__global__ __launch_bounds__(512) void k3_swap(
    const float* __restrict__ cbf, const int* __restrict__ idx_s,
    const int* __restrict__ idx_swap, const int* __restrict__ basis_idx1,
    const unsigned short* __restrict__ pack, const unsigned short* __restrict__ tT,
    float* __restrict__ out) {
  __shared__ __align__(16) unsigned short sWc[64 * 40];
  __shared__ int sSE[128];
  __shared__ int sB3[1024];
  __shared__ __align__(16) unsigned short sX[128 * 72];
  __shared__ __align__(16) unsigned short sY[128 * 136];
  const int tid = threadIdx.x;
  const int e0 = blockIdx.x * 128;

  ((uint2*)sWc)[tid] = ((const uint2*)(pack + PWC))[tid];
  if (tid < 128) {
    ((uint2*)sWc)[512 + tid] = ((const uint2*)(pack + PWC))[512 + tid];
    int f = idx_swap[min(e0 + tid, E - 1)];
    sSE[tid] = min(max(f, 0), E - 1);
  }
  __syncthreads();
  #pragma unroll
  for (int it = 0; it < 2; ++it) {
    int i = tid + it * 512;
    int f = sSE[i >> 3];
    int b = basis_idx1[idx_s[f] * 8 + (i & 7)];
    sB3[i] = min(max(b, 0), E - 1);
  }
  __syncthreads();

  const int lane = tid & 63, wv = tid >> 6;
  const int m = lane & 15, q = lane >> 4;

  bf16x8 bw[4];
  #pragma unroll
  for (int nt = 0; nt < 4; ++nt)
    bw[nt] = *(const bf16x8*)(sWc + (nt * 16 + m) * 40 + q * 8);

  for (int mt = 0; mt < 8; ++mt) {
    int le = wv * 16 + mt * 2;
    long long fa = sSE[le], fb = sSE[le + 1];
    xtile_gather_reduce(cbf, sB3, tT, bw, sX, wv, m, q, fa * 8, fb * 8, mt);
  }
  __syncthreads();

  ytile(pack, sX, sY, wv, m, q);
  __syncthreads();

  const int arow = wv * 16 + m;
  const f32x4 zero4 = {0.f, 0.f, 0.f, 0.f};
  f32x4 acc[8];
  #pragma unroll
  for (int nt = 0; nt < 8; ++nt) acc[nt] = zero4;
  #pragma unroll
  for (int kk = 0; kk < 4; ++kk) {
    bf16x8 a = *(const bf16x8*)(sY + arow * 136 + kk * 32 + q * 8);
    #pragma unroll
    for (int nt = 0; nt < 8; ++nt) {
      bf16x8 b = *(const bf16x8*)(pack + PWT + (nt * 16 + m) * 128 + kk * 32 + q * 8);
      acc[nt] = __builtin_amdgcn_mfma_f32_16x16x32_bf16(a, b, acc[nt], 0, 0, 0);
    }
  }
  #pragma unroll
  for (int nt = 0; nt < 8; ++nt)
    #pragma unroll
    for (int r = 0; r < 4; ++r) {
      int erow = e0 + wv * 16 + q * 4 + r;
      if (erow < E) {
        size_t o = (size_t)erow * 128 + nt * 16 + m;
        out[o] = (out[o] + silu_f(acc[nt][r])) * INV_SQRT_2;
      }
    }
}

extern "C" void kernel_launch(void* const* d_in, const int* in_sizes, int n_in,
                              void* d_out, int out_size, void* d_ws, size_t ws_size,
                              hipStream_t stream) {
  const float* m_st = (const float*)d_in[0];
  const float* rbf  = (const float*)d_in[1];
  const float* cbf  = (const float*)d_in[2];
  const int* idx_s  = (const int*)d_in[3];
  const int* idx_sw = (const int*)d_in[4];
  const int* bidx   = (const int*)d_in[5];
  const float* W1 = (const float*)d_in[6];   // W_m_rbf 128x128
  const float* W2 = (const float*)d_in[7];   // W_rbf   16x128
  const float* W3 = (const float*)d_in[8];   // W_m_cbf 128x64
  const float* Wc = (const float*)d_in[9];   // W_cbf   16x64
  const float* Wd = (const float*)d_in[10];  // W_dir   64x128
  const float* Ws = (const float*)d_in[11];  // W_st    128x128
  const float* Wt = (const float*)d_in[12];  // W_ts    128x128

  unsigned short* pack = (unsigned short*)d_ws;
  unsigned short* tT   = (unsigned short*)((char*)d_ws + OFF_T);
  float* zbuf = (ws_size >= WS_NEED_FAST) ? (float*)((char*)d_ws + OFF_Z) : nullptr;
  float* out = (float*)d_out;

  const int nb = (E + 127) / 128;
  k0_pack<<<(PACK_TOTAL + 255) / 256, 256, 0, stream>>>(W1, W2, W3, Wc, Wd, Ws, Wt, pack);
  k1_mbranch<<<nb, 512, 0, stream>>>(m_st, rbf, pack, tT);
  k2_fused<<<nb, 512, 0, stream>>>(cbf, idx_s, bidx, pack, tT, out, zbuf);
  if (zbuf) {
    k3_combine<<<(E * 32 + 255) / 256, 256, 0, stream>>>(idx_sw, zbuf, out);
  } else {
    k3_swap<<<nb, 512, 0, stream>>>(cbf, idx_s, idx_sw, bidx, pack, tT, out);
  }
}